// Round 6
// baseline (60794.366 us; speedup 1.0000x reference)
//
#include <hip/hip_runtime.h>
#include <hip/hip_bf16.h>

#define BB 2
#define SS 2048
#define NH 32
#define NKV 8
#define GQ (NH / NKV)
#define DD 128
#define QBLK 128
#define KVBLK 64
#define NQT (SS / QBLK)
#define NTHREADS 512

typedef __bf16 bf16x8 __attribute__((ext_vector_type(8)));
typedef short short8 __attribute__((ext_vector_type(8)));
typedef unsigned int u32x4 __attribute__((ext_vector_type(4)));

__device__ inline bf16x8 cvt_bf16x8(float4 a, float4 b) {
  bf16x8 r;
  r[0] = (__bf16)a.x; r[1] = (__bf16)a.y; r[2] = (__bf16)a.z; r[3] = (__bf16)a.w;
  r[4] = (__bf16)b.x; r[5] = (__bf16)b.y; r[6] = (__bf16)b.z; r[7] = (__bf16)b.w;
  return r;
}

__device__ inline float bf2f(short s) {
  unsigned u = ((unsigned)(unsigned short)s) << 16;
  return __builtin_bit_cast(float, u);
}

// DIFFERENTIAL PROBE: compute via known-good PLAIN bf16 LDS (R5 skeleton),
// while also writing/reading the R3 swizzled-bf16 buffers. Any byte-level
// mismatch between plain and swizzled reads raises a flag added to the
// output: K:+1e2, V:+1e4, P:+1e6. absmax identifies the guilty layer.
__global__ __launch_bounds__(NTHREADS, 1)
void attn_diff(const float* __restrict__ qp, const float* __restrict__ kp,
               const float* __restrict__ vp, float* __restrict__ op)
{
  __shared__ u32x4 qbuf[8 * 16 * 16];      // Q bf16 per-wave (32KB), as R3/R5
  __shared__ short kplain[KVBLK][DD];      // 16KB
  __shared__ short vplain[DD][KVBLK];      // 16KB (V^T)
  __shared__ short pplain[8][16][KVBLK];   // 16KB
  __shared__ u32x4 kswz[KVBLK * 16];       // 16KB, exact R3 layout
  __shared__ u32x4 vswz[DD * 8];           // 16KB, exact R3 layout
  __shared__ u32x4 pswz[8 * 16 * 8];       // 16KB, exact R3 layout

  const int tid  = threadIdx.x;
  const int wave = tid >> 6;
  const int lane = tid & 63;
  const int lhi  = lane >> 4;
  const int llo  = lane & 15;

  const int bid = blockIdx.x;
  const int bh  = bid % (BB * NH);
  const int qt  = NQT - 1 - bid / (BB * NH);
  const int b   = bh / NH;
  const int h   = bh % NH;
  const int kh  = h / GQ;

  const int q0 = qt * QBLK;
  const int qw = q0 + wave * 16;

  const float scale = 0.08838834764831845f;   // 1/sqrt(128)

  u32x4* qbuf_w = qbuf + wave * 256;
  {
    const float* qrow = qp + (((size_t)b * SS + (qw + llo)) * NH + h) * DD;
    #pragma unroll
    for (int kc = 0; kc < 4; ++kc) {
      const int d0 = kc * 32 + lhi * 8;
      float4 a = *(const float4*)(qrow + d0);
      float4 c = *(const float4*)(qrow + d0 + 4);
      a.x *= scale; a.y *= scale; a.z *= scale; a.w *= scale;
      c.x *= scale; c.y *= scale; c.z *= scale; c.w *= scale;
      qbuf_w[llo * 16 + kc * 4 + lhi] = __builtin_bit_cast(u32x4, cvt_bf16x8(a, c));
    }
  }

  float oaccf[8][4];
  #pragma unroll
  for (int f = 0; f < 8; ++f)
    #pragma unroll
    for (int j = 0; j < 4; ++j) oaccf[f][j] = 0.f;
  float m_i[4], l_i[4];
  #pragma unroll
  for (int j = 0; j < 4; ++j) { m_i[j] = -1e30f; l_i[j] = 0.f; }

  int kflag = 0, vflag = 0, pflag = 0;

  const int ntiles = q0 / KVBLK + 2;

  short* vswz_s = (short*)vswz;
  short* pswz_s = (short*)(pswz + wave * 128);
  const u32x4* pswz_w = pswz + wave * 128;

  for (int t = 0; t < ntiles; ++t) {
    const int t0 = t * KVBLK;
    __syncthreads();

    // ---- stage K tile: same bf16x8 value into plain AND swizzled ----
    #pragma unroll
    for (int it = 0; it < 2; ++it) {
      const int c   = tid + it * NTHREADS;
      const int row = c >> 4, c16 = c & 15;
      const float* src = kp + (((size_t)b * SS + (t0 + row)) * NKV + kh) * DD + c16 * 8;
      float4 a = *(const float4*)src;
      float4 d = *(const float4*)(src + 4);
      bf16x8 e = cvt_bf16x8(a, d);
      kswz[row * 16 + (c16 ^ (row & 7))] = __builtin_bit_cast(u32x4, e);
      short8 es = __builtin_bit_cast(short8, e);
      #pragma unroll
      for (int j = 0; j < 8; ++j) kplain[row][c16 * 8 + j] = es[j];
    }
    // ---- stage V^T tile: plain AND swizzled (exact R3 scatter) ----
    #pragma unroll
    for (int it = 0; it < 2; ++it) {
      const int c  = tid + it * NTHREADS;
      const int dg = c >> 6, tt = c & 63;
      const float* src = vp + (((size_t)b * SS + (t0 + tt)) * NKV + kh) * DD + dg * 8;
      float4 a  = *(const float4*)src;
      float4 d4 = *(const float4*)(src + 4);
      bf16x8 e = cvt_bf16x8(a, d4);
      short8 es = __builtin_bit_cast(short8, e);
      #pragma unroll
      for (int j = 0; j < 8; ++j) {
        const int dd = dg * 8 + j;
        vplain[dd][tt] = es[j];
        vswz_s[(dd * 8 + ((tt >> 3) ^ (dd & 7))) * 8 + (tt & 7)] = es[j];
      }
    }
    __syncthreads();

    if (t0 > qw + 15) continue;

    // ---- QK^T via plain path, comparing swizzled K reads ----
    float sf[4][4];
    #pragma unroll
    for (int cc = 0; cc < 4; ++cc) {
      const int r = cc * 16 + llo;
      #pragma unroll
      for (int j = 0; j < 4; ++j) {
        const int row = lhi * 4 + j;
        float acc = 0.f;
        #pragma unroll
        for (int s8 = 0; s8 < 16; ++s8) {
          short8 qv = __builtin_bit_cast(short8, qbuf_w[row * 16 + s8]);
          short8 ks = __builtin_bit_cast(short8, kswz[r * 16 + (s8 ^ (r & 7))]);
          #pragma unroll
          for (int e = 0; e < 8; ++e) {
            const short kpv = kplain[r][s8 * 8 + e];
            kflag |= (kpv != ks[e]);
            acc += bf2f(qv[e]) * bf2f(kpv);
          }
        }
        sf[cc][j] = acc;
      }
    }

    // ---- causal mask ----
    if (t0 + KVBLK - 1 > qw) {
      #pragma unroll
      for (int cc = 0; cc < 4; ++cc)
        #pragma unroll
        for (int j = 0; j < 4; ++j) {
          const int tg = t0 + cc * 16 + llo;
          const int qg = qw + lhi * 4 + j;
          if (tg > qg) sf[cc][j] = -1e30f;
        }
    }

    // ---- online softmax ----
    #pragma unroll
    for (int j = 0; j < 4; ++j) {
      float mx = fmaxf(fmaxf(sf[0][j], sf[1][j]), fmaxf(sf[2][j], sf[3][j]));
      #pragma unroll
      for (int off = 1; off < 16; off <<= 1)
        mx = fmaxf(mx, __shfl_xor(mx, off));
      const float mnew = fmaxf(m_i[j], mx);
      const float corr = __expf(m_i[j] - mnew);
      m_i[j] = mnew;
      float s = 0.f;
      #pragma unroll
      for (int cc = 0; cc < 4; ++cc) {
        const float p = __expf(sf[cc][j] - mnew);
        sf[cc][j] = p;
        s += p;
      }
      #pragma unroll
      for (int off = 1; off < 16; off <<= 1)
        s += __shfl_xor(s, off);
      l_i[j] = l_i[j] * corr + s;
      #pragma unroll
      for (int f = 0; f < 8; ++f) oaccf[f][j] *= corr;
    }

    // ---- P -> plain AND swizzled (exact R3 scatter) ----
    #pragma unroll
    for (int cc = 0; cc < 4; ++cc) {
      #pragma unroll
      for (int j = 0; j < 4; ++j) {
        const int row = lhi * 4 + j;
        const int col = cc * 16 + llo;
        const short pb = __builtin_bit_cast(short, (__bf16)sf[cc][j]);
        pplain[wave][row][col] = pb;
        pswz_s[(row * 8 + ((col >> 3) ^ (row & 7))) * 8 + (col & 7)] = pb;
      }
    }

    asm volatile("s_waitcnt lgkmcnt(0)" ::: "memory");
    __builtin_amdgcn_sched_barrier(0);

    // ---- PV via plain path, comparing swizzled P and V reads ----
    #pragma unroll
    for (int f = 0; f < 8; ++f) {
      const int dd = f * 16 + llo;
      #pragma unroll
      for (int j = 0; j < 4; ++j) {
        const int row = lhi * 4 + j;
        float acc = 0.f;
        #pragma unroll
        for (int s8 = 0; s8 < 8; ++s8) {
          short8 pv = __builtin_bit_cast(short8, pswz_w[row * 8 + (s8 ^ (row & 7))]);
          short8 vv = __builtin_bit_cast(short8, vswz[dd * 8 + (s8 ^ (dd & 7))]);
          #pragma unroll
          for (int e = 0; e < 8; ++e) {
            const short ppv = pplain[wave][row][s8 * 8 + e];
            const short vvv = vplain[dd][s8 * 8 + e];
            pflag |= (ppv != pv[e]);
            vflag |= (vvv != vv[e]);
            acc += bf2f(ppv) * bf2f(vvv);
          }
        }
        oaccf[f][j] += acc;
      }
    }
  }

  // ---- epilogue + flag injection ----
  const float flagadd = kflag * 100.f + vflag * 10000.f + pflag * 1000000.f;
  #pragma unroll
  for (int j = 0; j < 4; ++j) {
    const float inv = 1.f / l_i[j];
    const int qg = qw + lhi * 4 + j;
    float* orow = op + (((size_t)b * SS + qg) * NH + h) * DD;
    #pragma unroll
    for (int f = 0; f < 8; ++f)
      orow[f * 16 + llo] = oaccf[f][j] * inv + flagadd;
  }
}

extern "C" void kernel_launch(void* const* d_in, const int* in_sizes, int n_in,
                              void* d_out, int out_size, void* d_ws, size_t ws_size,
                              hipStream_t stream) {
  const float* q = (const float*)d_in[0];
  const float* k = (const float*)d_in[1];
  const float* v = (const float*)d_in[2];
  float* out = (float*)d_out;
  dim3 grid(BB * NH * NQT);
  dim3 block(NTHREADS);
  attn_diff<<<grid, block, 0, stream>>>(q, k, v, out);
}